// Round 1
// 1666.244 us; speedup vs baseline: 1.2179x; 1.2179x over previous
//
#include <hip/hip_runtime.h>

#define NB 8
#define NH 8
#define LSEQ 2048
#define DH 64
#define NBH (NB * NH)

typedef __attribute__((ext_vector_type(8))) short bf16x8;
typedef __attribute__((ext_vector_type(4))) float f32x4;

__device__ __forceinline__ short f2bf(float f) {
    union { float f; unsigned u; } v; v.f = f;
    unsigned r = v.u + 0x7fffu + ((v.u >> 16) & 1u);
    return (short)(r >> 16);
}

__device__ __forceinline__ void load_q_frags(const float* __restrict__ qp,
                                             bf16x8& a0, bf16x8& a1) {
    float4 f0 = *(const float4*)(qp);
    float4 f1 = *(const float4*)(qp + 4);
    float4 f2 = *(const float4*)(qp + 32);
    float4 f3 = *(const float4*)(qp + 36);
    a0[0]=f2bf(f0.x); a0[1]=f2bf(f0.y); a0[2]=f2bf(f0.z); a0[3]=f2bf(f0.w);
    a0[4]=f2bf(f1.x); a0[5]=f2bf(f1.y); a0[6]=f2bf(f1.z); a0[7]=f2bf(f1.w);
    a1[0]=f2bf(f2.x); a1[1]=f2bf(f2.y); a1[2]=f2bf(f2.z); a1[3]=f2bf(f2.w);
    a1[4]=f2bf(f3.x); a1[5]=f2bf(f3.y); a1[6]=f2bf(f3.z); a1[7]=f2bf(f3.w);
}

// ---------------- K0a: K (f32) -> Kbf (bf16, same [bh][l][d] layout) --------
__global__ __launch_bounds__(256)
void conv_k(const float* __restrict__ K, short* __restrict__ Kbf) {
    const size_t i = ((size_t)blockIdx.x * 256 + threadIdx.x) * 8;
    float4 f0 = *(const float4*)(K + i);
    float4 f1 = *(const float4*)(K + i + 4);
    bf16x8 o;
    o[0]=f2bf(f0.x); o[1]=f2bf(f0.y); o[2]=f2bf(f0.z); o[3]=f2bf(f0.w);
    o[4]=f2bf(f1.x); o[5]=f2bf(f1.y); o[6]=f2bf(f1.z); o[7]=f2bf(f1.w);
    *(bf16x8*)(Kbf + i) = o;
}

// ---------------- K0b: V[bh][l][d] f32 -> Vt[bh][d][l] bf16 -----------------
// LDS tile 64x64 bf16 with 8-col-chunk XOR swizzle (chunk ^= d>>3) to avoid
// the 8-way write conflict a linear [64][64] layout would have.
__global__ __launch_bounds__(256)
void transp_v(const float* __restrict__ V, short* __restrict__ Vt) {
    __shared__ __align__(16) short t[DH][64];
    const int tid = threadIdx.x;
    const int bh = blockIdx.x >> 5;
    const int l0 = (blockIdx.x & 31) << 6;
    const float* vb = V + ((size_t)bh * LSEQ + l0) * DH;
    #pragma unroll
    for (int p = 0; p < 4; ++p) {
        const int l = (p << 4) + (tid >> 4);
        const int d0 = (tid & 15) << 2;
        float4 f = *(const float4*)(vb + (size_t)l * DH + d0);
        const int lc = l >> 3, li = l & 7;
        const int g = d0 >> 3;  // (d0+j)>>3 == d0>>3 for j=0..3 since d0%8 in {0,4}
        t[d0 + 0][((lc ^ g) << 3) + li] = f2bf(f.x);
        t[d0 + 1][((lc ^ g) << 3) + li] = f2bf(f.y);
        t[d0 + 2][((lc ^ g) << 3) + li] = f2bf(f.z);
        t[d0 + 3][((lc ^ g) << 3) + li] = f2bf(f.w);
    }
    __syncthreads();
    const int d = tid >> 2;
    const int s2 = (tid & 3) << 1;    // even chunk index 0,2,4,6
    const int g = d >> 3;
    short* ob = Vt + ((size_t)bh * DH + d) * LSEQ + l0 + (s2 << 3);
    *(bf16x8*)(ob)     = *(const bf16x8*)&t[d][(s2 ^ g) << 3];
    *(bf16x8*)(ob + 8) = *(const bf16x8*)&t[d][((s2 + 1) ^ g) << 3];
}

// ---------------- K1: rowsums of exp(QK^T/64) -------------------------------
// WG = 64 query rows (4 independent waves x 16 rows, all 2048 keys). Uses the
// SAME bf16 fragments + MFMA chain + __expf as the main kernel -> bitwise
// identical S values, so normalization is exactly consistent.
__global__ __launch_bounds__(256, 4)
void rowsum_k(const float* __restrict__ Q, const short* __restrict__ Kbf,
              float* __restrict__ rsum) {
    const int tid = threadIdx.x;
    const int lane = tid & 63;
    const int w = tid >> 6;
    const int q16 = lane & 15;
    const int quad = lane >> 4;
    const int nb_ = ((blockIdx.x & 7) << 8) + (blockIdx.x >> 3); // XCD swizzle
    const int bh = nb_ >> 5;
    const int qbase = ((nb_ & 31) << 6) + (w << 4);
    const size_t qkv0 = (size_t)bh * (LSEQ * DH);

    bf16x8 aq0, aq1;
    load_q_frags(Q + qkv0 + (size_t)(qbase + q16) * DH + quad * 8, aq0, aq1);

    float rs0 = 0.f, rs1 = 0.f, rs2 = 0.f, rs3 = 0.f;
    const short* kb = Kbf + qkv0 + (size_t)q16 * DH + quad * 8;
    for (int c = 0; c < 64; ++c) {
        const short* kp = kb + (size_t)(c << 5) * DH;
        bf16x8 b00 = *(const bf16x8*)(kp);
        bf16x8 b01 = *(const bf16x8*)(kp + 32);
        bf16x8 b10 = *(const bf16x8*)(kp + 16 * DH);
        bf16x8 b11 = *(const bf16x8*)(kp + 16 * DH + 32);
        f32x4 s0 = {0.f,0.f,0.f,0.f}, s1 = {0.f,0.f,0.f,0.f};
        s0 = __builtin_amdgcn_mfma_f32_16x16x32_bf16(aq0, b00, s0, 0, 0, 0);
        s0 = __builtin_amdgcn_mfma_f32_16x16x32_bf16(aq1, b01, s0, 0, 0, 0);
        s1 = __builtin_amdgcn_mfma_f32_16x16x32_bf16(aq0, b10, s1, 0, 0, 0);
        s1 = __builtin_amdgcn_mfma_f32_16x16x32_bf16(aq1, b11, s1, 0, 0, 0);
        rs0 += __expf(s0[0] * 0.015625f) + __expf(s1[0] * 0.015625f);
        rs1 += __expf(s0[1] * 0.015625f) + __expf(s1[1] * 0.015625f);
        rs2 += __expf(s0[2] * 0.015625f) + __expf(s1[2] * 0.015625f);
        rs3 += __expf(s0[3] * 0.015625f) + __expf(s1[3] * 0.015625f);
    }
    #pragma unroll
    for (int m = 1; m < 16; m <<= 1) {
        rs0 += __shfl_xor(rs0, m, 64);
        rs1 += __shfl_xor(rs1, m, 64);
        rs2 += __shfl_xor(rs2, m, 64);
        rs3 += __shfl_xor(rs3, m, 64);
    }
    if (q16 == 0) {
        float* rp = rsum + (size_t)bh * LSEQ + qbase + (quad << 2);
        rp[0] = rs0; rp[1] = rs1; rp[2] = rs2; rp[3] = rs3;
    }
}

// ---------------- K2: main — att + res in one streaming pass ----------------
// WG = 64 query rows, 4 fully independent waves (no barriers). Per 32-key
// chunk: 4 QK MFMAs -> exp*linv -> direct f32 att stores (nontemporal) +
// bf16 P via a 1.25KB per-wave LDS tile (pad-40 rows: <=2-way banks) ->
// 4 PV MFMAs. LDS total 5KB -> occupancy is VGPR-bound, not LDS-bound.
__global__ __launch_bounds__(256, 4)
void sdpa_main(const float* __restrict__ Q, const short* __restrict__ Kbf,
               const short* __restrict__ Vt, const float* __restrict__ rsum,
               float* __restrict__ out_res, float* __restrict__ out_att) {
    __shared__ __align__(16) short pbuf[4][16][40];
    const int tid = threadIdx.x;
    const int lane = tid & 63;
    const int w = tid >> 6;
    const int q16 = lane & 15;
    const int quad = lane >> 4;

    const int nb_ = ((blockIdx.x & 7) << 8) + (blockIdx.x >> 3); // XCD swizzle
    const int bh = nb_ >> 5;
    const int qbase = ((nb_ & 31) << 6) + (w << 4);
    const size_t qkv0 = (size_t)bh * (LSEQ * DH);

    bf16x8 aq0, aq1;
    load_q_frags(Q + qkv0 + (size_t)(qbase + q16) * DH + quad * 8, aq0, aq1);

    float linv[4];
    {
        const float* rp = rsum + (size_t)bh * LSEQ + qbase + (quad << 2);
        linv[0] = 1.0f / rp[0];
        linv[1] = 1.0f / rp[1];
        linv[2] = 1.0f / rp[2];
        linv[3] = 1.0f / rp[3];
    }

    f32x4 acc0 = {0.f,0.f,0.f,0.f}, acc1 = {0.f,0.f,0.f,0.f};
    f32x4 acc2 = {0.f,0.f,0.f,0.f}, acc3 = {0.f,0.f,0.f,0.f};

    const short* kb = Kbf + qkv0 + (size_t)q16 * DH + quad * 8;
    const short* vb = Vt + (size_t)bh * (DH * LSEQ) + (size_t)q16 * LSEQ + quad * 8;
    float* ab = out_att + ((size_t)bh * LSEQ + qbase + (quad << 2)) * LSEQ + q16;
    short* pw = &pbuf[w][quad << 2][q16];        // C-layout writes
    const short* pr = &pbuf[w][q16][quad << 3];  // A-frag reads (16B aligned)

    for (int c = 0; c < 64; ++c) {
        const int col0 = c << 5;
        const short* kp = kb + (size_t)col0 * DH;
        bf16x8 b00 = *(const bf16x8*)(kp);
        bf16x8 b01 = *(const bf16x8*)(kp + 32);
        bf16x8 b10 = *(const bf16x8*)(kp + 16 * DH);
        bf16x8 b11 = *(const bf16x8*)(kp + 16 * DH + 32);
        f32x4 s0 = {0.f,0.f,0.f,0.f}, s1 = {0.f,0.f,0.f,0.f};
        s0 = __builtin_amdgcn_mfma_f32_16x16x32_bf16(aq0, b00, s0, 0, 0, 0);
        s0 = __builtin_amdgcn_mfma_f32_16x16x32_bf16(aq1, b01, s0, 0, 0, 0);
        s1 = __builtin_amdgcn_mfma_f32_16x16x32_bf16(aq0, b10, s1, 0, 0, 0);
        s1 = __builtin_amdgcn_mfma_f32_16x16x32_bf16(aq1, b11, s1, 0, 0, 0);

        // normalized P: f32 att store + bf16 to LDS for the PV A-fragment
        #pragma unroll
        for (int r = 0; r < 4; ++r) {
            const float p0 = __expf(s0[r] * 0.015625f) * linv[r];
            const float p1 = __expf(s1[r] * 0.015625f) * linv[r];
            __builtin_nontemporal_store(p0, ab + (size_t)r * LSEQ + col0);
            __builtin_nontemporal_store(p1, ab + (size_t)r * LSEQ + col0 + 16);
            pw[r * 40]      = f2bf(p0);
            pw[r * 40 + 16] = f2bf(p1);
        }

        const bf16x8 pa = *(const bf16x8*)pr;  // same-wave LDS RAW: in-order DS
        const short* vp = vb + col0;
        acc0 = __builtin_amdgcn_mfma_f32_16x16x32_bf16(pa, *(const bf16x8*)(vp),             acc0, 0, 0, 0);
        acc1 = __builtin_amdgcn_mfma_f32_16x16x32_bf16(pa, *(const bf16x8*)(vp + 16 * LSEQ), acc1, 0, 0, 0);
        acc2 = __builtin_amdgcn_mfma_f32_16x16x32_bf16(pa, *(const bf16x8*)(vp + 32 * LSEQ), acc2, 0, 0, 0);
        acc3 = __builtin_amdgcn_mfma_f32_16x16x32_bf16(pa, *(const bf16x8*)(vp + 48 * LSEQ), acc3, 0, 0, 0);
    }

    float* rb = out_res + qkv0 + (size_t)(qbase + (quad << 2)) * DH + q16;
    #pragma unroll
    for (int r = 0; r < 4; ++r) {
        __builtin_nontemporal_store(acc0[r], rb + (size_t)r * DH);
        __builtin_nontemporal_store(acc1[r], rb + (size_t)r * DH + 16);
        __builtin_nontemporal_store(acc2[r], rb + (size_t)r * DH + 32);
        __builtin_nontemporal_store(acc3[r], rb + (size_t)r * DH + 48);
    }
}

extern "C" void kernel_launch(void* const* d_in, const int* in_sizes, int n_in,
                              void* d_out, int out_size, void* d_ws, size_t ws_size,
                              hipStream_t stream) {
    const float* Q = (const float*)d_in[0];
    const float* K = (const float*)d_in[1];
    const float* V = (const float*)d_in[2];
    float* out_res = (float*)d_out;
    float* out_att = out_res + (size_t)NB * NH * LSEQ * DH;

    // workspace: Kbf (16MB) | Vt (16MB) | rowsums (512KB)  => ~32.5 MiB
    short* Kbf = (short*)d_ws;
    short* Vt  = Kbf + (size_t)NBH * LSEQ * DH;
    float* rsum = (float*)(Vt + (size_t)NBH * LSEQ * DH);

    conv_k  <<<dim3(4096), dim3(256), 0, stream>>>(K, Kbf);
    transp_v<<<dim3(2048), dim3(256), 0, stream>>>(V, Vt);
    rowsum_k<<<dim3(2048), dim3(256), 0, stream>>>(Q, Kbf, rsum);
    sdpa_main<<<dim3(2048), dim3(256), 0, stream>>>(Q, Kbf, Vt, rsum, out_res, out_att);
}